// Round 9
// baseline (315.390 us; speedup 1.0000x reference)
//
#include <hip/hip_runtime.h>

// Inputs are f32 (verified: R2-R5 passed via runtime-detect f32 path; reference
// declares float32 and output absmax matched at f32 write-back). bf16 staging
// internally; f32 accumulate; f32 out.
//
// Session notes:
// - spmm_dual4 (1 row/wave, wave-uniform) = 113 us proven best; group/persistent
//   variants worse. FETCH pinned ~383 MB, rate pinned 3.4-3.9 TB/s =>
//   random-512B-gather roofline. Do not restructure spmm without a byte cut.
// - DO NOT fuse colsum->sigmoid via atomicAdd into a 256-float region (R3).
// - R7: depth-1 register prefetch = null. Prefetch hides min(compute,latency);
//   agg loads ~2000cyc >> compute ~300cyc.
// - R8 WIN (-19 us): LDS-stage all 5 agg tiles via global_load_lds issued
//   up-front (deep MLP), granule-permuted k-major (conflict-free ds_read_b128).
// - R9: prep had 19.2K tiny blocks, VALUBusy 6%/HBM 27%/occ 54% => block
//   dispatch overhead theory. Grid-stride to 2.6K blocks, SAME per-thread body
//   (R5 lesson: don't change the access width, only the loop structure).

// ---------- bf16 bit helpers ----------
__device__ __forceinline__ float b2f(unsigned short s) {
    union { unsigned int u; float f; } c; c.u = ((unsigned int)s) << 16; return c.f;
}
__device__ __forceinline__ unsigned short f2b(float f) {
    union { float f; unsigned int u; } c; c.f = f;
    unsigned int u = c.u;
    unsigned int r = u + 0x7FFFu + ((u >> 16) & 1u);   // RNE
    return (unsigned short)(r >> 16);
}
__device__ __forceinline__ unsigned int pack2(float lo, float hi) {
    return ((unsigned int)f2b(hi) << 16) | f2b(lo);
}
__device__ __forceinline__ void fma8(float* a, float v, uint4 w) {
    a[0] = fmaf(v, b2f((unsigned short)w.x), a[0]);
    a[1] = fmaf(v, b2f((unsigned short)(w.x >> 16)), a[1]);
    a[2] = fmaf(v, b2f((unsigned short)w.y), a[2]);
    a[3] = fmaf(v, b2f((unsigned short)(w.y >> 16)), a[3]);
    a[4] = fmaf(v, b2f((unsigned short)w.z), a[4]);
    a[5] = fmaf(v, b2f((unsigned short)(w.z >> 16)), a[5]);
    a[6] = fmaf(v, b2f((unsigned short)w.w), a[6]);
    a[7] = fmaf(v, b2f((unsigned short)(w.w >> 16)), a[7]);
}

typedef __attribute__((ext_vector_type(8))) short bf16x8;
typedef __attribute__((ext_vector_type(4))) float f32x4;

#define T_TILES 5
#define RP_BLOCKS 512
#define W1_BLOCKS 16
#define CV_BLOCKS 2048

// ---------- K1: fused prep (grid-stride): rowptr | W1 -> bf16 | x/xt -> bf16 ----------
// xint layout: node row = 512 B: [x 128 bf16][x_tilde 128 bf16]
// Sections: [0,RP_BLOCKS) rowptr (4 positions/thread, int4 fast path);
//           [RP,RP+W1) W1 convert; rest: x/xt convert, identical 8-elem body.
__global__ __launch_bounds__(256) void prep(
    const int* __restrict__ row, int* __restrict__ rp, int n, int e,
    const float* __restrict__ w1, unsigned short* __restrict__ w1b,
    const float* __restrict__ x, const float* __restrict__ xt,
    unsigned short* __restrict__ xint, int total8)
{
    int b = blockIdx.x, tid = threadIdx.x;
    if (b < RP_BLOCKS) {                            // --- build row_ptr ---
        int nq = e / 4 + 1;                         // quads covering positions 0..e
        for (int q = b * 256 + tid; q < nq; q += RP_BLOCKS * 256) {
            int i0 = q * 4;
            if (i0 >= 4 && i0 + 3 < e) {            // fast path: all middle positions
                int prev = row[i0 - 1];
                int4 v = *(const int4*)(row + i0);
                if (v.x > prev) for (int rr = prev + 1; rr <= v.x; ++rr) rp[rr] = i0;
                if (v.y > v.x)  for (int rr = v.x + 1; rr <= v.y; ++rr) rp[rr] = i0 + 1;
                if (v.z > v.y)  for (int rr = v.y + 1; rr <= v.z; ++rr) rp[rr] = i0 + 2;
                if (v.w > v.z)  for (int rr = v.z + 1; rr <= v.w; ++rr) rp[rr] = i0 + 3;
            } else {
                for (int j = 0; j < 4; ++j) {
                    int i = i0 + j;
                    if (i > e) break;
                    if (i == 0) {
                        int r1 = row[0];
                        for (int rr = 0; rr <= r1; ++rr) rp[rr] = 0;
                    } else if (i == e) {
                        int r0 = row[e - 1];
                        for (int rr = r0 + 1; rr <= n; ++rr) rp[rr] = e;
                    } else {
                        int r0 = row[i - 1], r1 = row[i];
                        for (int rr = r0 + 1; rr <= r1; ++rr) rp[rr] = i;
                    }
                }
            }
        }
    } else if (b < RP_BLOCKS + W1_BLOCKS) {         // --- W1 -> bf16 ---
        for (int i = (b - RP_BLOCKS) * 256 + tid; i < 32768; i += W1_BLOCKS * 256)
            w1b[i] = f2b(w1[i]);
    } else {                                        // --- x/xt conversion ---
        int cb = b - RP_BLOCKS - W1_BLOCKS;
        int tot2 = 2 * total8;
        for (int c = cb * 256 + tid; c < tot2; c += CV_BLOCKS * 256) {
            int which = (c >= total8) ? 1 : 0;
            int i = c - which * total8;             // 8-elem chunk index
            const float* s = which ? xt : x;
            int node = i >> 4, sub = i & 15;
            const float4* p = (const float4*)s + (size_t)i * 2;
            float4 a = p[0], bb = p[1];
            uint4 o;
            o.x = pack2(a.x, a.y);  o.y = pack2(a.z, a.w);
            o.z = pack2(bb.x, bb.y); o.w = pack2(bb.z, bb.w);
            *(uint4*)(xint + (size_t)node * 256 + which * 128 + sub * 8) = o;
        }
    }
}

// ---------- K2: dual SpMM; col/vals preloaded per 64-edge chunk, 16 edges/iter ----------
// lane = g*16 + l: group g handles edges {base+4u+g}, lane l handles dims [8l,8l+8)
// PROVEN BEST body (113 us single-launch). DO NOT TOUCH.
__global__ __launch_bounds__(256) void spmm_dual4(
    const unsigned short* __restrict__ xint, const float* __restrict__ vals,
    const int* __restrict__ col, const int* __restrict__ row_ptr,
    unsigned short* __restrict__ aggx, unsigned short* __restrict__ aggt,
    int r_base, int r_end)
{
    int wave = threadIdx.x >> 6;
    int lane = threadIdx.x & 63;
    int g = lane >> 4, l = lane & 15;
    int r = r_base + blockIdx.x * 4 + wave;
    if (r >= r_end) return;
    int e0 = row_ptr[r], e1 = row_ptr[r + 1];
    float ax[8], at[8];
#pragma unroll
    for (int d = 0; d < 8; ++d) { ax[d] = 0.f; at[d] = 0.f; }
    for (int chunk = e0; chunk < e1; chunk += 64) {
        int m = e1 - chunk; if (m > 64) m = 64;     // edges in this chunk
        int ce = chunk + (lane < m ? lane : m - 1); // coalesced preload (clamped)
        int cc = col[ce];
        float cv = (lane < m) ? vals[ce] : 0.f;
        for (int base = 0; base < m; base += 16) {
            uint4 xw[4], tw[4];
            float fv[4];
#pragma unroll
            for (int u = 0; u < 4; ++u) {
                int idx = base + 4 * u + g;
                int idc = idx < m ? idx : m - 1;    // clamp: duplicate line is cache-hot
                int c  = __shfl(cc, idc, 64);
                float v = __shfl(cv, idc, 64);
                fv[u] = (idx < m) ? v : 0.f;
                const uint4* p = (const uint4*)(xint + (size_t)c * 256);
                xw[u] = p[l];
                tw[u] = p[16 + l];
            }
#pragma unroll
            for (int u = 0; u < 4; ++u) { fma8(ax, fv[u], xw[u]); fma8(at, fv[u], tw[u]); }
        }
    }
#pragma unroll
    for (int d = 0; d < 8; ++d) {
        ax[d] += __shfl_xor(ax[d], 16, 64);
        ax[d] += __shfl_xor(ax[d], 32, 64);
        at[d] += __shfl_xor(at[d], 16, 64);
        at[d] += __shfl_xor(at[d], 32, 64);
    }
    if (g == 0) {
        uint4 o;
        o.x = pack2(ax[0], ax[1]); o.y = pack2(ax[2], ax[3]);
        o.z = pack2(ax[4], ax[5]); o.w = pack2(ax[6], ax[7]);
        ((uint4*)(aggx + (size_t)r * 128))[l] = o;
    } else if (g == 1) {
        uint4 o;
        o.x = pack2(at[0], at[1]); o.y = pack2(at[2], at[3]);
        o.z = pack2(at[4], at[5]); o.w = pack2(at[6], at[7]);
        ((uint4*)(aggt + (size_t)r * 128))[l] = o;
    }
}

// ---------- staging helper: async-copy tile granules k-major into LDS ----------
// Thread t stages global granule (nl=t&15, quad=(t>>4)&3, k=t>>6) of tile i into
// linear LDS slot i*4096 + t*16. Compute-side read for (lane, k) is then at
// (k*64 + lane)*16 bytes -> consecutive per lane, conflict-free ds_read_b128.
__device__ __forceinline__ void stage_tile(
    const short* agg, size_t tile, unsigned short* smem, int i, int tid)
{
    int snl = tid & 15, squad = (tid >> 4) & 3, sk = tid >> 6;
    const unsigned short* src = (const unsigned short*)agg
        + tile * 2048 + (size_t)snl * 128 + squad * 8 + sk * 32;
    __builtin_amdgcn_global_load_lds(
        (const __attribute__((address_space(1))) unsigned int*)src,
        (__attribute__((address_space(3))) unsigned int*)(smem + (size_t)i * 2048 + tid * 8),
        16, 0, 0);
}

// ---------- K3: GEMM + colsum; agg tiles LDS-staged (deep async); W1 in regs ----------
// C/D layout: col = nl, row = quad*4 + r. Column sum => sum over r, then quad bits.
// partial layout: [out_dim 256][block nb]  (coalesced for the reducer)
__global__ __launch_bounds__(256) void gemm_colsum3(
    const short* __restrict__ aggb, const short* __restrict__ w1,
    const float* __restrict__ pa, float* __restrict__ partial, int ntiles, int nb)
{
    __shared__ unsigned short smem[T_TILES * 2048];
    int tid = threadIdx.x;
    int w = tid >> 6, lane = tid & 63;
    int nl = lane & 15, quad = lane >> 4;
    int t0 = blockIdx.x * T_TILES;
    int nt = ntiles - t0; if (nt > T_TILES) nt = T_TILES;
    // issue ALL tile DMAs up-front (deep queue, no VGPR cost)
    for (int i = 0; i < nt; ++i)
        stage_tile(aggb, (size_t)(t0 + i), smem, i, tid);
    // W1 fragment loads overlap the DMA
    const short* brow = w1 + ((size_t)(4 * w) * 16 + nl) * 128 + quad * 8;
    bf16x8 bf[4][4];
#pragma unroll
    for (int j = 0; j < 4; ++j)
#pragma unroll
        for (int k = 0; k < 4; ++k)
            bf[j][k] = *(const bf16x8*)(brow + j * 2048 + k * 32);
    float aslope = pa[0];
    float cs[4] = {0.f, 0.f, 0.f, 0.f};
    __syncthreads();                    // drains vmcnt: DMA + W1 complete
    for (int i = 0; i < nt; ++i) {
        bf16x8 af[4];
#pragma unroll
        for (int k = 0; k < 4; ++k)
            af[k] = *(const bf16x8*)(smem + (size_t)i * 2048 + (k * 64 + lane) * 8);
        f32x4 acc[4];
#pragma unroll
        for (int j = 0; j < 4; ++j) acc[j] = (f32x4){0.f, 0.f, 0.f, 0.f};
#pragma unroll
        for (int k = 0; k < 4; ++k)
#pragma unroll
            for (int j = 0; j < 4; ++j)
                acc[j] = __builtin_amdgcn_mfma_f32_16x16x32_bf16(af[k], bf[j][k], acc[j], 0, 0, 0);
#pragma unroll
        for (int j = 0; j < 4; ++j)
#pragma unroll
            for (int r = 0; r < 4; ++r) {
                float z = acc[j][r];
                cs[j] += (z >= 0.f) ? z : aslope * z;
            }
    }
#pragma unroll
    for (int j = 0; j < 4; ++j) {
        cs[j] += __shfl_xor(cs[j], 16, 64);   // reduce rows: quad bits only
        cs[j] += __shfl_xor(cs[j], 32, 64);
    }
    if (quad == 0)
#pragma unroll
        for (int j = 0; j < 4; ++j)
            partial[(size_t)((4 * w + j) * 16 + nl) * nb + blockIdx.x] = cs[j];
}

// ---------- K4: reduce partials + sigmoid -> s (one block per out dim) ----------
__global__ __launch_bounds__(256) void reduce_sig(
    const float* __restrict__ partial, int nb, float* __restrict__ s_out, float invN)
{
    __shared__ float l[256];
    int d = blockIdx.x, tid = threadIdx.x;
    float s = 0.f;
    for (int i = tid; i < nb; i += 256)
        s += partial[(size_t)d * nb + i];
    l[tid] = s;
    __syncthreads();
    for (int o = 128; o > 0; o >>= 1) {
        if (tid < o) l[tid] += l[tid + o];
        __syncthreads();
    }
    if (tid == 0) s_out[d] = 1.f / (1.f + expf(-l[0] * invN));
}

// ---------- K5: v = w_bil @ s (one block per output dim, wave reduce) ----------
__global__ __launch_bounds__(64) void compute_v2(
    const float* __restrict__ s_in, const float* __restrict__ wbil,
    float* __restrict__ v)
{
    int d = blockIdx.x;
    int lane = threadIdx.x;
    const float* wrow = wbil + (size_t)d * 256;
    float acc = 0.f;
#pragma unroll
    for (int j = 0; j < 4; ++j)
        acc = fmaf(wrow[j * 64 + lane], s_in[j * 64 + lane], acc);
    acc += __shfl_xor(acc, 1, 64);
    acc += __shfl_xor(acc, 2, 64);
    acc += __shfl_xor(acc, 4, 64);
    acc += __shfl_xor(acc, 8, 64);
    acc += __shfl_xor(acc, 16, 64);
    acc += __shfl_xor(acc, 32, 64);
    if (lane == 0) v[d] = acc;
}

// ---------- K6: GEMM + dot with v; agg tiles LDS-staged (deep async) ----------
__global__ __launch_bounds__(256) void gemm_dp2(
    const short* __restrict__ aggx, const short* __restrict__ aggt,
    const short* __restrict__ w1, const float* __restrict__ pa,
    const float* __restrict__ v, float* __restrict__ out, int ntiles, int N)
{
    __shared__ unsigned short smem[T_TILES * 2048];
    __shared__ float dpbuf[4][T_TILES * 16];
    int tid = threadIdx.x;
    int w = tid >> 6, lane = tid & 63;
    int nl = lane & 15, quad = lane >> 4;
    const short* agg = blockIdx.y ? aggt : aggx;
    int t0 = blockIdx.x * T_TILES;
    int nt = ntiles - t0; if (nt > T_TILES) nt = T_TILES;
    // issue ALL tile DMAs up-front
    for (int i = 0; i < nt; ++i)
        stage_tile(agg, (size_t)(t0 + i), smem, i, tid);
    // W1 fragment + v loads overlap the DMA
    const short* brow = w1 + ((size_t)(4 * w) * 16 + nl) * 128 + quad * 8;
    bf16x8 bf[4][4];
#pragma unroll
    for (int j = 0; j < 4; ++j)
#pragma unroll
        for (int k = 0; k < 4; ++k)
            bf[j][k] = *(const bf16x8*)(brow + j * 2048 + k * 32);
    float vreg[4];
#pragma unroll
    for (int j = 0; j < 4; ++j) vreg[j] = v[(4 * w + j) * 16 + nl];
    float aslope = pa[0];
    __syncthreads();                    // drains vmcnt: DMA + W1 + v complete
    for (int i = 0; i < nt; ++i) {
        bf16x8 af[4];
#pragma unroll
        for (int k = 0; k < 4; ++k)
            af[k] = *(const bf16x8*)(smem + (size_t)i * 2048 + (k * 64 + lane) * 8);
        f32x4 acc[4];
#pragma unroll
        for (int j = 0; j < 4; ++j) acc[j] = (f32x4){0.f, 0.f, 0.f, 0.f};
#pragma unroll
        for (int k = 0; k < 4; ++k)
#pragma unroll
            for (int j = 0; j < 4; ++j)
                acc[j] = __builtin_amdgcn_mfma_f32_16x16x32_bf16(af[k], bf[j][k], acc[j], 0, 0, 0);
        float p[4] = {0.f, 0.f, 0.f, 0.f};
#pragma unroll
        for (int j = 0; j < 4; ++j)
#pragma unroll
            for (int r = 0; r < 4; ++r) {
                float z = acc[j][r];
                float h = (z >= 0.f) ? z : aslope * z;
                p[r] = fmaf(h, vreg[j], p[r]);
            }
#pragma unroll
        for (int r = 0; r < 4; ++r) {   // reduce over nl bits (16 cols of the slice)
            p[r] += __shfl_xor(p[r], 1, 64);
            p[r] += __shfl_xor(p[r], 2, 64);
            p[r] += __shfl_xor(p[r], 4, 64);
            p[r] += __shfl_xor(p[r], 8, 64);
        }
        if (nl == 0)
#pragma unroll
            for (int r = 0; r < 4; ++r)
                dpbuf[w][i * 16 + quad * 4 + r] = p[r];
    }
    __syncthreads();
    int nloc = nt * 16;
    for (int idx = tid; idx < nloc; idx += 256) {
        float s = dpbuf[0][idx] + dpbuf[1][idx] + dpbuf[2][idx] + dpbuf[3][idx];
        out[(size_t)blockIdx.y * N + (size_t)t0 * 16 + idx] = s;
    }
}

extern "C" void kernel_launch(void* const* d_in, const int* in_sizes, int n_in,
                              void* d_out, int out_size, void* d_ws, size_t ws_size,
                              hipStream_t stream) {
    const float* x    = (const float*)d_in[0];
    const float* xt   = (const float*)d_in[1];
    const float* vals = (const float*)d_in[2];
    const int* row    = (const int*)d_in[3];
    const int* col    = (const int*)d_in[4];
    const float* w1   = (const float*)d_in[5];
    const float* pa   = (const float*)d_in[6];
    const float* wb   = (const float*)d_in[7];

    const int N = in_sizes[0] / 128;
    const int E = in_sizes[2];
    const int ntiles = (N + 15) / 16;
    const int cs_blocks = (ntiles + T_TILES - 1) / T_TILES;

    char* ws = (char*)d_ws;
    size_t off = 0;
    auto alloc = [&](size_t bytes) { char* p = ws + off; off = (off + bytes + 255) & ~(size_t)255; return p; };
    int* row_ptr         = (int*)alloc((size_t)(N + 1) * 4);
    unsigned short* aggx = (unsigned short*)alloc((size_t)N * 128 * 2);
    unsigned short* aggt = (unsigned short*)alloc((size_t)N * 128 * 2);
    unsigned short* w1b  = (unsigned short*)alloc(32768 * 2);
    float* partial       = (float*)alloc((size_t)cs_blocks * 256 * 4);
    float* svec          = (float*)alloc(256 * 4);
    float* vvec          = (float*)alloc(256 * 4);
    unsigned short* xint = (unsigned short*)alloc((size_t)N * 256 * 2);  // x|xt interleaved bf16

    int total8 = (N * 128) / 8;
    prep<<<RP_BLOCKS + W1_BLOCKS + CV_BLOCKS, 256, 0, stream>>>(
        row, row_ptr, N, E, w1, w1b, x, xt, xint, total8);

    spmm_dual4<<<(N + 3) / 4, 256, 0, stream>>>(
        xint, vals, col, row_ptr, aggx, aggt, 0, N);

    gemm_colsum3<<<cs_blocks, 256, 0, stream>>>(
        (const short*)aggx, (const short*)w1b, pa, partial, ntiles, cs_blocks);
    reduce_sig<<<256, 256, 0, stream>>>(partial, cs_blocks, svec, 1.0f / (float)N);
    compute_v2<<<256, 64, 0, stream>>>(svec, wb, vvec);
    gemm_dp2<<<dim3(cs_blocks, 2), 256, 0, stream>>>(
        (const short*)aggx, (const short*)aggt, (const short*)w1b, pa, vvec,
        (float*)d_out, ntiles, N);
}

// Round 10
// 308.982 us; speedup vs baseline: 1.0207x; 1.0207x over previous
//
#include <hip/hip_runtime.h>

// Inputs are f32 (verified: R2-R5 passed via runtime-detect f32 path; reference
// declares float32 and output absmax matched at f32 write-back). bf16 staging
// internally; f32 accumulate; f32 out.
//
// Session notes:
// - spmm_dual4 (1 row/wave, wave-uniform) = 113 us proven best; group/persistent
//   variants worse. FETCH pinned ~383 MB, rate pinned 3.4-3.9 TB/s =>
//   random-512B-gather roofline. Do not restructure spmm without a byte cut.
// - DO NOT fuse colsum->sigmoid via atomicAdd into a 256-float region (R3).
// - R7: depth-1 register prefetch = null (hides min(compute,latency)).
// - R8 WIN (-19 us): LDS-stage all agg tiles via global_load_lds issued
//   up-front (deep MLP), granule-permuted k-major (conflict-free ds_read_b128).
// - R9: grid-stride prep = null => dispatch-overhead theory falsified; prep is
//   latency-intrinsic. Reverted to R8-exact prep (proven 313.2).
// - R10: T_TILES 5->10 in the STAGED regime (new tradeoff: 2x deeper DMA queue,
//   halved W1-reload traffic; occupancy cap not binding at these grid sizes).

// ---------- bf16 bit helpers ----------
__device__ __forceinline__ float b2f(unsigned short s) {
    union { unsigned int u; float f; } c; c.u = ((unsigned int)s) << 16; return c.f;
}
__device__ __forceinline__ unsigned short f2b(float f) {
    union { float f; unsigned int u; } c; c.f = f;
    unsigned int u = c.u;
    unsigned int r = u + 0x7FFFu + ((u >> 16) & 1u);   // RNE
    return (unsigned short)(r >> 16);
}
__device__ __forceinline__ unsigned int pack2(float lo, float hi) {
    return ((unsigned int)f2b(hi) << 16) | f2b(lo);
}
__device__ __forceinline__ void fma8(float* a, float v, uint4 w) {
    a[0] = fmaf(v, b2f((unsigned short)w.x), a[0]);
    a[1] = fmaf(v, b2f((unsigned short)(w.x >> 16)), a[1]);
    a[2] = fmaf(v, b2f((unsigned short)w.y), a[2]);
    a[3] = fmaf(v, b2f((unsigned short)(w.y >> 16)), a[3]);
    a[4] = fmaf(v, b2f((unsigned short)w.z), a[4]);
    a[5] = fmaf(v, b2f((unsigned short)(w.z >> 16)), a[5]);
    a[6] = fmaf(v, b2f((unsigned short)w.w), a[6]);
    a[7] = fmaf(v, b2f((unsigned short)(w.w >> 16)), a[7]);
}

typedef __attribute__((ext_vector_type(8))) short bf16x8;
typedef __attribute__((ext_vector_type(4))) float f32x4;

#define T_TILES 10

// ---------- K1: fused prep: rowptr | W1 -> bf16 | x/x_tilde -> interleaved bf16 ----------
// xint layout: node row = 512 B: [x 128 bf16][x_tilde 128 bf16]
// R8-exact (proven 313.2 us config).
__global__ __launch_bounds__(256) void prep(
    const int* __restrict__ row, int* __restrict__ rp, int n, int e, int rb,
    const float* __restrict__ w1, unsigned short* __restrict__ w1b, int pb,
    const float* __restrict__ x, const float* __restrict__ xt,
    unsigned short* __restrict__ xint, int total8, int halfcb)
{
    int b = blockIdx.x, tid = threadIdx.x;
    if (b < rb) {                                   // --- build row_ptr ---
        int i = b * 256 + tid;
        if (i > e) return;
        if (i == 0) {
            int r1 = row[0];
            for (int rr = 0; rr <= r1; ++rr) rp[rr] = 0;
        } else if (i == e) {
            int r0 = row[e - 1];
            for (int rr = r0 + 1; rr <= n; ++rr) rp[rr] = e;
        } else {
            int r0 = row[i - 1], r1 = row[i];
            for (int rr = r0 + 1; rr <= r1; ++rr) rp[rr] = i;
        }
    } else if (b < rb + pb) {                       // --- W1 -> bf16 ---
        int i = (b - rb) * 256 + tid;               // 0..32767
        if (i < 32768) w1b[i] = f2b(w1[i]);
    } else {                                        // --- x conversion (interleaved) ---
        int cb = b - rb - pb;
        int which = (cb >= halfcb) ? 1 : 0;
        int i = (cb - which * halfcb) * 256 + tid;  // 8-elem chunk index
        if (i >= total8) return;
        const float* s = which ? xt : x;
        int node = i >> 4, sub = i & 15;
        const float4* p = (const float4*)s + (size_t)i * 2;
        float4 a = p[0], bb = p[1];
        uint4 o;
        o.x = pack2(a.x, a.y);  o.y = pack2(a.z, a.w);
        o.z = pack2(bb.x, bb.y); o.w = pack2(bb.z, bb.w);
        *(uint4*)(xint + (size_t)node * 256 + which * 128 + sub * 8) = o;
    }
}

// ---------- K2: dual SpMM; col/vals preloaded per 64-edge chunk, 16 edges/iter ----------
// lane = g*16 + l: group g handles edges {base+4u+g}, lane l handles dims [8l,8l+8)
// PROVEN BEST body (113 us single-launch). DO NOT TOUCH.
__global__ __launch_bounds__(256) void spmm_dual4(
    const unsigned short* __restrict__ xint, const float* __restrict__ vals,
    const int* __restrict__ col, const int* __restrict__ row_ptr,
    unsigned short* __restrict__ aggx, unsigned short* __restrict__ aggt,
    int r_base, int r_end)
{
    int wave = threadIdx.x >> 6;
    int lane = threadIdx.x & 63;
    int g = lane >> 4, l = lane & 15;
    int r = r_base + blockIdx.x * 4 + wave;
    if (r >= r_end) return;
    int e0 = row_ptr[r], e1 = row_ptr[r + 1];
    float ax[8], at[8];
#pragma unroll
    for (int d = 0; d < 8; ++d) { ax[d] = 0.f; at[d] = 0.f; }
    for (int chunk = e0; chunk < e1; chunk += 64) {
        int m = e1 - chunk; if (m > 64) m = 64;     // edges in this chunk
        int ce = chunk + (lane < m ? lane : m - 1); // coalesced preload (clamped)
        int cc = col[ce];
        float cv = (lane < m) ? vals[ce] : 0.f;
        for (int base = 0; base < m; base += 16) {
            uint4 xw[4], tw[4];
            float fv[4];
#pragma unroll
            for (int u = 0; u < 4; ++u) {
                int idx = base + 4 * u + g;
                int idc = idx < m ? idx : m - 1;    // clamp: duplicate line is cache-hot
                int c  = __shfl(cc, idc, 64);
                float v = __shfl(cv, idc, 64);
                fv[u] = (idx < m) ? v : 0.f;
                const uint4* p = (const uint4*)(xint + (size_t)c * 256);
                xw[u] = p[l];
                tw[u] = p[16 + l];
            }
#pragma unroll
            for (int u = 0; u < 4; ++u) { fma8(ax, fv[u], xw[u]); fma8(at, fv[u], tw[u]); }
        }
    }
#pragma unroll
    for (int d = 0; d < 8; ++d) {
        ax[d] += __shfl_xor(ax[d], 16, 64);
        ax[d] += __shfl_xor(ax[d], 32, 64);
        at[d] += __shfl_xor(at[d], 16, 64);
        at[d] += __shfl_xor(at[d], 32, 64);
    }
    if (g == 0) {
        uint4 o;
        o.x = pack2(ax[0], ax[1]); o.y = pack2(ax[2], ax[3]);
        o.z = pack2(ax[4], ax[5]); o.w = pack2(ax[6], ax[7]);
        ((uint4*)(aggx + (size_t)r * 128))[l] = o;
    } else if (g == 1) {
        uint4 o;
        o.x = pack2(at[0], at[1]); o.y = pack2(at[2], at[3]);
        o.z = pack2(at[4], at[5]); o.w = pack2(at[6], at[7]);
        ((uint4*)(aggt + (size_t)r * 128))[l] = o;
    }
}

// ---------- staging helper: async-copy tile granules k-major into LDS ----------
// Thread t stages global granule (nl=t&15, quad=(t>>4)&3, k=t>>6) of tile i into
// linear LDS slot i*4096 + t*16. Compute-side read for (lane, k) is then at
// (k*64 + lane)*16 bytes -> consecutive per lane, conflict-free ds_read_b128.
__device__ __forceinline__ void stage_tile(
    const short* agg, size_t tile, unsigned short* smem, int i, int tid)
{
    int snl = tid & 15, squad = (tid >> 4) & 3, sk = tid >> 6;
    const unsigned short* src = (const unsigned short*)agg
        + tile * 2048 + (size_t)snl * 128 + squad * 8 + sk * 32;
    __builtin_amdgcn_global_load_lds(
        (const __attribute__((address_space(1))) unsigned int*)src,
        (__attribute__((address_space(3))) unsigned int*)(smem + (size_t)i * 2048 + tid * 8),
        16, 0, 0);
}

// ---------- K3: GEMM + colsum; agg tiles LDS-staged (deep async); W1 in regs ----------
// C/D layout: col = nl, row = quad*4 + r. Column sum => sum over r, then quad bits.
// partial layout: [out_dim 256][block nb]  (coalesced for the reducer)
__global__ __launch_bounds__(256) void gemm_colsum3(
    const short* __restrict__ aggb, const short* __restrict__ w1,
    const float* __restrict__ pa, float* __restrict__ partial, int ntiles, int nb)
{
    __shared__ unsigned short smem[T_TILES * 2048];
    int tid = threadIdx.x;
    int w = tid >> 6, lane = tid & 63;
    int nl = lane & 15, quad = lane >> 4;
    int t0 = blockIdx.x * T_TILES;
    int nt = ntiles - t0; if (nt > T_TILES) nt = T_TILES;
    // issue ALL tile DMAs up-front (deep queue, no VGPR cost)
    for (int i = 0; i < nt; ++i)
        stage_tile(aggb, (size_t)(t0 + i), smem, i, tid);
    // W1 fragment loads overlap the DMA
    const short* brow = w1 + ((size_t)(4 * w) * 16 + nl) * 128 + quad * 8;
    bf16x8 bf[4][4];
#pragma unroll
    for (int j = 0; j < 4; ++j)
#pragma unroll
        for (int k = 0; k < 4; ++k)
            bf[j][k] = *(const bf16x8*)(brow + j * 2048 + k * 32);
    float aslope = pa[0];
    float cs[4] = {0.f, 0.f, 0.f, 0.f};
    __syncthreads();                    // drains vmcnt: DMA + W1 complete
    for (int i = 0; i < nt; ++i) {
        bf16x8 af[4];
#pragma unroll
        for (int k = 0; k < 4; ++k)
            af[k] = *(const bf16x8*)(smem + (size_t)i * 2048 + (k * 64 + lane) * 8);
        f32x4 acc[4];
#pragma unroll
        for (int j = 0; j < 4; ++j) acc[j] = (f32x4){0.f, 0.f, 0.f, 0.f};
#pragma unroll
        for (int k = 0; k < 4; ++k)
#pragma unroll
            for (int j = 0; j < 4; ++j)
                acc[j] = __builtin_amdgcn_mfma_f32_16x16x32_bf16(af[k], bf[j][k], acc[j], 0, 0, 0);
#pragma unroll
        for (int j = 0; j < 4; ++j)
#pragma unroll
            for (int r = 0; r < 4; ++r) {
                float z = acc[j][r];
                cs[j] += (z >= 0.f) ? z : aslope * z;
            }
    }
#pragma unroll
    for (int j = 0; j < 4; ++j) {
        cs[j] += __shfl_xor(cs[j], 16, 64);   // reduce rows: quad bits only
        cs[j] += __shfl_xor(cs[j], 32, 64);
    }
    if (quad == 0)
#pragma unroll
        for (int j = 0; j < 4; ++j)
            partial[(size_t)((4 * w + j) * 16 + nl) * nb + blockIdx.x] = cs[j];
}

// ---------- K4: reduce partials + sigmoid -> s (one block per out dim) ----------
__global__ __launch_bounds__(256) void reduce_sig(
    const float* __restrict__ partial, int nb, float* __restrict__ s_out, float invN)
{
    __shared__ float l[256];
    int d = blockIdx.x, tid = threadIdx.x;
    float s = 0.f;
    for (int i = tid; i < nb; i += 256)
        s += partial[(size_t)d * nb + i];
    l[tid] = s;
    __syncthreads();
    for (int o = 128; o > 0; o >>= 1) {
        if (tid < o) l[tid] += l[tid + o];
        __syncthreads();
    }
    if (tid == 0) s_out[d] = 1.f / (1.f + expf(-l[0] * invN));
}

// ---------- K5: v = w_bil @ s (one block per output dim, wave reduce) ----------
__global__ __launch_bounds__(64) void compute_v2(
    const float* __restrict__ s_in, const float* __restrict__ wbil,
    float* __restrict__ v)
{
    int d = blockIdx.x;
    int lane = threadIdx.x;
    const float* wrow = wbil + (size_t)d * 256;
    float acc = 0.f;
#pragma unroll
    for (int j = 0; j < 4; ++j)
        acc = fmaf(wrow[j * 64 + lane], s_in[j * 64 + lane], acc);
    acc += __shfl_xor(acc, 1, 64);
    acc += __shfl_xor(acc, 2, 64);
    acc += __shfl_xor(acc, 4, 64);
    acc += __shfl_xor(acc, 8, 64);
    acc += __shfl_xor(acc, 16, 64);
    acc += __shfl_xor(acc, 32, 64);
    if (lane == 0) v[d] = acc;
}

// ---------- K6: GEMM + dot with v; agg tiles LDS-staged (deep async) ----------
__global__ __launch_bounds__(256) void gemm_dp2(
    const short* __restrict__ aggx, const short* __restrict__ aggt,
    const short* __restrict__ w1, const float* __restrict__ pa,
    const float* __restrict__ v, float* __restrict__ out, int ntiles, int N)
{
    __shared__ unsigned short smem[T_TILES * 2048];
    __shared__ float dpbuf[4][T_TILES * 16];
    int tid = threadIdx.x;
    int w = tid >> 6, lane = tid & 63;
    int nl = lane & 15, quad = lane >> 4;
    const short* agg = blockIdx.y ? aggt : aggx;
    int t0 = blockIdx.x * T_TILES;
    int nt = ntiles - t0; if (nt > T_TILES) nt = T_TILES;
    // issue ALL tile DMAs up-front
    for (int i = 0; i < nt; ++i)
        stage_tile(agg, (size_t)(t0 + i), smem, i, tid);
    // W1 fragment + v loads overlap the DMA
    const short* brow = w1 + ((size_t)(4 * w) * 16 + nl) * 128 + quad * 8;
    bf16x8 bf[4][4];
#pragma unroll
    for (int j = 0; j < 4; ++j)
#pragma unroll
        for (int k = 0; k < 4; ++k)
            bf[j][k] = *(const bf16x8*)(brow + j * 2048 + k * 32);
    float vreg[4];
#pragma unroll
    for (int j = 0; j < 4; ++j) vreg[j] = v[(4 * w + j) * 16 + nl];
    float aslope = pa[0];
    __syncthreads();                    // drains vmcnt: DMA + W1 + v complete
    for (int i = 0; i < nt; ++i) {
        bf16x8 af[4];
#pragma unroll
        for (int k = 0; k < 4; ++k)
            af[k] = *(const bf16x8*)(smem + (size_t)i * 2048 + (k * 64 + lane) * 8);
        f32x4 acc[4];
#pragma unroll
        for (int j = 0; j < 4; ++j) acc[j] = (f32x4){0.f, 0.f, 0.f, 0.f};
#pragma unroll
        for (int k = 0; k < 4; ++k)
#pragma unroll
            for (int j = 0; j < 4; ++j)
                acc[j] = __builtin_amdgcn_mfma_f32_16x16x32_bf16(af[k], bf[j][k], acc[j], 0, 0, 0);
        float p[4] = {0.f, 0.f, 0.f, 0.f};
#pragma unroll
        for (int j = 0; j < 4; ++j)
#pragma unroll
            for (int r = 0; r < 4; ++r) {
                float z = acc[j][r];
                float h = (z >= 0.f) ? z : aslope * z;
                p[r] = fmaf(h, vreg[j], p[r]);
            }
#pragma unroll
        for (int r = 0; r < 4; ++r) {   // reduce over nl bits (16 cols of the slice)
            p[r] += __shfl_xor(p[r], 1, 64);
            p[r] += __shfl_xor(p[r], 2, 64);
            p[r] += __shfl_xor(p[r], 4, 64);
            p[r] += __shfl_xor(p[r], 8, 64);
        }
        if (nl == 0)
#pragma unroll
            for (int r = 0; r < 4; ++r)
                dpbuf[w][i * 16 + quad * 4 + r] = p[r];
    }
    __syncthreads();
    int nloc = nt * 16;
    for (int idx = tid; idx < nloc; idx += 256) {
        float s = dpbuf[0][idx] + dpbuf[1][idx] + dpbuf[2][idx] + dpbuf[3][idx];
        out[(size_t)blockIdx.y * N + (size_t)t0 * 16 + idx] = s;
    }
}

extern "C" void kernel_launch(void* const* d_in, const int* in_sizes, int n_in,
                              void* d_out, int out_size, void* d_ws, size_t ws_size,
                              hipStream_t stream) {
    const float* x    = (const float*)d_in[0];
    const float* xt   = (const float*)d_in[1];
    const float* vals = (const float*)d_in[2];
    const int* row    = (const int*)d_in[3];
    const int* col    = (const int*)d_in[4];
    const float* w1   = (const float*)d_in[5];
    const float* pa   = (const float*)d_in[6];
    const float* wb   = (const float*)d_in[7];

    const int N = in_sizes[0] / 128;
    const int E = in_sizes[2];
    const int ntiles = (N + 15) / 16;
    const int cs_blocks = (ntiles + T_TILES - 1) / T_TILES;

    char* ws = (char*)d_ws;
    size_t off = 0;
    auto alloc = [&](size_t bytes) { char* p = ws + off; off = (off + bytes + 255) & ~(size_t)255; return p; };
    int* row_ptr         = (int*)alloc((size_t)(N + 1) * 4);
    unsigned short* aggx = (unsigned short*)alloc((size_t)N * 128 * 2);
    unsigned short* aggt = (unsigned short*)alloc((size_t)N * 128 * 2);
    unsigned short* w1b  = (unsigned short*)alloc(32768 * 2);
    float* partial       = (float*)alloc((size_t)cs_blocks * 256 * 4);
    float* svec          = (float*)alloc(256 * 4);
    float* vvec          = (float*)alloc(256 * 4);
    unsigned short* xint = (unsigned short*)alloc((size_t)N * 256 * 2);  // x|xt interleaved bf16

    int rb = (E + 1 + 255) / 256;
    int pb = 128;
    int total8 = (N * 128) / 8;
    int halfcb = (total8 + 255) / 256;
    prep<<<rb + pb + 2 * halfcb, 256, 0, stream>>>(
        row, row_ptr, N, E, rb, w1, w1b, pb, x, xt, xint, total8, halfcb);

    spmm_dual4<<<(N + 3) / 4, 256, 0, stream>>>(
        xint, vals, col, row_ptr, aggx, aggt, 0, N);

    gemm_colsum3<<<cs_blocks, 256, 0, stream>>>(
        (const short*)aggx, (const short*)w1b, pa, partial, ntiles, cs_blocks);
    reduce_sig<<<256, 256, 0, stream>>>(partial, cs_blocks, svec, 1.0f / (float)N);
    compute_v2<<<256, 64, 0, stream>>>(svec, wb, vvec);
    gemm_dp2<<<dim3(cs_blocks, 2), 256, 0, stream>>>(
        (const short*)aggx, (const short*)aggt, (const short*)w1b, pa, vvec,
        (float*)d_out, ntiles, N);
}